// Round 1
// baseline (497.547 us; speedup 1.0000x reference)
//
#include <hip/hip_runtime.h>

#define B_ 8
#define C_ 16
#define H_ 240
#define W_ 320
#define N_ (H_*W_)

// R = I + sin(th)*K + (1-cos(th))*K^2, K = skew(w/th), th = |w| + 1e-12
__device__ __forceinline__ void twist2mat_dev(float w0, float w1, float w2, float R[9]) {
    float th = sqrtf(w0*w0 + w1*w1 + w2*w2) + 1e-12f;
    float ax = w0/th, ay = w1/th, az = w2/th;
    float s = sinf(th), c = cosf(th), ic = 1.0f - c;
    R[0] = 1.0f + ic*(ax*ax - 1.0f);
    R[1] = -s*az + ic*ax*ay;
    R[2] =  s*ay + ic*ax*az;
    R[3] =  s*az + ic*ax*ay;
    R[4] = 1.0f + ic*(ay*ay - 1.0f);
    R[5] = -s*ax + ic*ay*az;
    R[6] = -s*ay + ic*ax*az;
    R[7] =  s*ax + ic*ay*az;
    R[8] = 1.0f + ic*(az*az - 1.0f);
}

__global__ void init_kernel(const float* __restrict__ twist0, float* __restrict__ RT,
                            float* __restrict__ accum) {
    int tid = threadIdx.x;
    if (tid < B_*27) accum[tid] = 0.0f;
    if (tid < B_) {
        const float* w = twist0 + tid*6;
        float R[9];
        twist2mat_dev(w[0], w[1], w[2], R);
        float* rt = RT + tid*12;
        #pragma unroll
        for (int i = 0; i < 9; i++) rt[i] = R[i];
        rt[9] = w[3]; rt[10] = w[4]; rt[11] = w[5];
    }
}

__launch_bounds__(256)
__global__ void reduce_kernel(const float* __restrict__ x0, const float* __restrict__ x1,
                              const float* __restrict__ invD0, const float* __restrict__ invD1,
                              const float* __restrict__ sigma0, const float* __restrict__ sigma1,
                              const float* __restrict__ Kmat, const float* __restrict__ RT,
                              float* __restrict__ accum)
{
    const int b = blockIdx.y;
    const int pix = blockIdx.x * 256 + threadIdx.x;   // N_ divisible by 256
    const int h = pix / W_;
    const int w = pix - h*W_;

    const float fx = Kmat[b*4+0], fy = Kmat[b*4+1], cx = Kmat[b*4+2], cy = Kmat[b*4+3];
    const float* rt = RT + b*12;
    const float R00=rt[0],R01=rt[1],R02=rt[2],R10=rt[3],R11=rt[4],R12=rt[5],
                R20=rt[6],R21=rt[7],R22=rt[8];
    const float t0=rt[9], t1=rt[10], t2=rt[11];

    float acc[27];
    #pragma unroll
    for (int j = 0; j < 27; j++) acc[j] = 0.0f;

    const float px = ((float)w - cx) / fx;
    const float py = ((float)h - cy) / fy;
    const float d  = invD0[b*N_ + pix];

    const float x_ = R00*px + R01*py + R02 + t0*d;
    const float y_ = R10*px + R11*py + R12 + t1*d;
    const float s_ = R20*px + R21*py + R22 + t2*d;
    const float u = x_/s_*fx + cx;
    const float v = y_/s_*fy + cy;
    const float inv_z = d / s_;

    // bilinear setup on clipped coords (shared by invD1 / x1 / sigma1 sampling)
    const float uc = fminf(fmaxf(u, 0.0f), (float)(W_-1));
    const float vc = fminf(fmaxf(v, 0.0f), (float)(H_-1));
    const float x0f = floorf(uc), y0f = floorf(vc);
    const float wx = uc - x0f, wy = vc - y0f;
    const int x0i = (int)x0f, y0i = (int)y0f;
    const int x1i = min(x0i+1, W_-1), y1i = min(y0i+1, H_-1);
    const float w00 = (1.0f-wx)*(1.0f-wy), w01 = wx*(1.0f-wy);
    const float w10 = (1.0f-wx)*wy,        w11 = wx*wy;
    const int i00 = y0i*W_+x0i, i01 = y0i*W_+x1i, i10 = y1i*W_+x0i, i11 = y1i*W_+x1i;

    // occlusion check (per pixel)
    const float* dz = invD1 + b*N_;
    const float zw = dz[i00]*w00 + dz[i01]*w01 + dz[i10]*w10 + dz[i11]*w11;
    const bool inlier = inv_z > zw - 0.1f;
    const bool inview = (u > 0.0f) && (u < (float)W_) && (v > 0.0f) && (v < (float)H_);
    const bool valid  = inlier && inview;

    if (valid) {
        // per-pixel warp jacobians A = fx*dx_dp, B = fy*dy_dp
        const float xy = px*py;
        const float Av[6] = { -xy*fx, (1.0f+px*px)*fx, -py*fx, d*fx, 0.0f, -d*px*fx };
        const float Bv[6] = { -(1.0f+py*py)*fy, xy*fy, px*fy, 0.0f, d*fy, -d*py*fy };

        const int hm = max(h-1,0), hp = min(h+1,H_-1);
        const int wm = max(w-1,0), wp = min(w+1,W_-1);

        float Swxx=0.f, Swxy=0.f, Swyy=0.f, Srx=0.f, Sry=0.f;
        const float* x0b = x0     + (size_t)b*C_*N_;
        const float* x1b = x1     + (size_t)b*C_*N_;
        const float* s0b = sigma0 + (size_t)b*C_*N_;
        const float* s1b = sigma1 + (size_t)b*C_*N_;
        for (int c = 0; c < C_; c++) {
            const float* xc = x0b + c*N_;
            // sobel with edge-clamped pad, normalized
            const float tl = xc[hm*W_+wm], tc_ = xc[hm*W_+w], tr = xc[hm*W_+wp];
            const float ml = xc[h*W_+wm],                     mr = xc[h*W_+wp];
            const float bl = xc[hp*W_+wm], bc_ = xc[hp*W_+w], br = xc[hp*W_+wp];
            const float dx = tr - tl + 2.0f*(mr - ml) + (br - bl);
            const float dy = bl - tl + 2.0f*(bc_ - tc_) + (br - tr);
            const float mag = sqrtf(dx*dx + dy*dy + 1e-8f);
            const float gx = dx/mag, gy = dy/mag;

            const float* x1c = x1b + c*N_;
            const float fr = x1c[i00]*w00 + x1c[i01]*w01 + x1c[i10]*w10 + x1c[i11]*w11;
            const float* s1c = s1b + c*N_;
            const float sr = s1c[i00]*w00 + s1c[i01]*w01 + s1c[i10]*w10 + s1c[i11]*w11;
            const float s0v = s0b[c*N_ + pix];
            const float sig2 = sr*sr + s0v*s0v;
            const float inv_s2 = 1.0f / sig2;
            const float res = fr - xc[pix];
            Swxx += gx*gx*inv_s2;
            Swxy += gx*gy*inv_s2;
            Swyy += gy*gy*inv_s2;
            Srx  += gx*res*inv_s2;
            Sry  += gy*res*inv_s2;
        }
        int idx = 0;
        #pragma unroll
        for (int k = 0; k < 6; k++) {
            #pragma unroll
            for (int l = k; l < 6; l++) {
                acc[idx++] = Swxx*Av[k]*Av[l] + Swxy*(Av[k]*Bv[l] + Bv[k]*Av[l]) + Swyy*Bv[k]*Bv[l];
            }
        }
        #pragma unroll
        for (int k = 0; k < 6; k++) acc[21+k] = Srx*Av[k] + Sry*Bv[k];
    }

    // block reduction: wave shuffle -> LDS -> one atomic per block per accumulator
    const int lane = threadIdx.x & 63;
    const int wave = threadIdx.x >> 6;
    __shared__ float red[4][27];
    #pragma unroll
    for (int j = 0; j < 27; j++) {
        float vv = acc[j];
        vv += __shfl_down(vv, 32);
        vv += __shfl_down(vv, 16);
        vv += __shfl_down(vv, 8);
        vv += __shfl_down(vv, 4);
        vv += __shfl_down(vv, 2);
        vv += __shfl_down(vv, 1);
        if (lane == 0) red[wave][j] = vv;
    }
    __syncthreads();
    if (threadIdx.x < 27) {
        float s = red[0][threadIdx.x] + red[1][threadIdx.x] + red[2][threadIdx.x] + red[3][threadIdx.x];
        atomicAdd(&accum[b*27 + threadIdx.x], s);
    }
}

__global__ void solve_kernel(float* __restrict__ RT, float* __restrict__ accum,
                             float* __restrict__ out)
{
    const int b = threadIdx.x;
    if (b >= B_) return;
    float* ac = accum + b*27;

    float Hm[6][6];
    {
        int idx = 0;
        for (int k = 0; k < 6; k++)
            for (int l = k; l < 6; l++) { Hm[k][l] = ac[idx]; Hm[l][k] = ac[idx]; idx++; }
    }
    const float trace = Hm[0][0]+Hm[1][1]+Hm[2][2]+Hm[3][3]+Hm[4][4]+Hm[5][5];
    const float lam = trace * 1e-6f;

    float M[6][7];
    for (int i = 0; i < 6; i++) {
        for (int j = 0; j < 6; j++) M[i][j] = Hm[i][j];
        M[i][i] += lam;
        M[i][6] = ac[21+i];
    }
    // zero accumulators for the next iteration
    for (int j = 0; j < 27; j++) ac[j] = 0.0f;

    // Gaussian elimination with partial pivoting
    for (int k = 0; k < 6; k++) {
        int p = k; float best = fabsf(M[k][k]);
        for (int i = k+1; i < 6; i++) {
            float a = fabsf(M[i][k]);
            if (a > best) { best = a; p = i; }
        }
        if (p != k) {
            for (int j = k; j < 7; j++) { float tmp = M[k][j]; M[k][j] = M[p][j]; M[p][j] = tmp; }
        }
        const float inv = 1.0f / M[k][k];
        for (int i = k+1; i < 6; i++) {
            const float f = M[i][k] * inv;
            for (int j = k; j < 7; j++) M[i][j] -= f * M[k][j];
        }
    }
    float xi[6];
    for (int i = 5; i >= 0; i--) {
        float s = M[i][6];
        for (int j = i+1; j < 6; j++) s -= M[i][j]*xi[j];
        xi[i] = s / M[i][i];
    }

    float dR[9];
    twist2mat_dev(-xi[0], -xi[1], -xi[2], dR);
    const float dt0 = -(dR[0]*xi[3] + dR[1]*xi[4] + dR[2]*xi[5]);
    const float dt1 = -(dR[3]*xi[3] + dR[4]*xi[4] + dR[5]*xi[5]);
    const float dt2 = -(dR[6]*xi[3] + dR[7]*xi[4] + dR[8]*xi[5]);

    float* rt = RT + b*12;
    float R[9];
    #pragma unroll
    for (int i = 0; i < 9; i++) R[i] = rt[i];
    const float t0 = rt[9], t1 = rt[10], t2 = rt[11];

    const float nt0 = R[0]*dt0 + R[1]*dt1 + R[2]*dt2 + t0;
    const float nt1 = R[3]*dt0 + R[4]*dt1 + R[5]*dt2 + t1;
    const float nt2 = R[6]*dt0 + R[7]*dt1 + R[8]*dt2 + t2;

    float nR[9];
    #pragma unroll
    for (int i = 0; i < 3; i++)
        #pragma unroll
        for (int j = 0; j < 3; j++)
            nR[i*3+j] = R[i*3+0]*dR[0*3+j] + R[i*3+1]*dR[1*3+j] + R[i*3+2]*dR[2*3+j];

    #pragma unroll
    for (int i = 0; i < 9; i++) rt[i] = nR[i];
    rt[9] = nt0; rt[10] = nt1; rt[11] = nt2;

    float* ob = out + b*12;
    #pragma unroll
    for (int i = 0; i < 9; i++) ob[i] = nR[i];
    ob[9] = nt0; ob[10] = nt1; ob[11] = nt2;
}

extern "C" void kernel_launch(void* const* d_in, const int* in_sizes, int n_in,
                              void* d_out, int out_size, void* d_ws, size_t ws_size,
                              hipStream_t stream) {
    const float* twist0 = (const float*)d_in[0];
    const float* x0     = (const float*)d_in[1];
    const float* x1     = (const float*)d_in[2];
    const float* invD0  = (const float*)d_in[3];
    const float* invD1  = (const float*)d_in[4];
    const float* sigma0 = (const float*)d_in[5];
    const float* sigma1 = (const float*)d_in[6];
    const float* Kmat   = (const float*)d_in[7];
    float* out = (float*)d_out;

    float* RT    = (float*)d_ws;        // B*12 floats
    float* accum = RT + B_*12;          // B*27 floats

    hipLaunchKernelGGL(init_kernel, dim3(1), dim3(256), 0, stream, twist0, RT, accum);

    dim3 grid(N_/256, B_);
    for (int it = 0; it < 3; ++it) {
        hipLaunchKernelGGL(reduce_kernel, grid, dim3(256), 0, stream,
                           x0, x1, invD0, invD1, sigma0, sigma1, Kmat, RT, accum);
        hipLaunchKernelGGL(solve_kernel, dim3(1), dim3(64), 0, stream, RT, accum, out);
    }
}

// Round 2
// 432.042 us; speedup vs baseline: 1.1516x; 1.1516x over previous
//
#include <hip/hip_runtime.h>

#define B_ 8
#define C_ 16
#define H_ 240
#define W_ 320
#define N_ (H_*W_)

__device__ __forceinline__ void twist2mat_dev(float w0, float w1, float w2, float R[9]) {
    float th = sqrtf(w0*w0 + w1*w1 + w2*w2) + 1e-12f;
    float ax = w0/th, ay = w1/th, az = w2/th;
    float s = sinf(th), c = cosf(th), ic = 1.0f - c;
    R[0] = 1.0f + ic*(ax*ax - 1.0f);
    R[1] = -s*az + ic*ax*ay;
    R[2] =  s*ay + ic*ax*az;
    R[3] =  s*az + ic*ax*ay;
    R[4] = 1.0f + ic*(ay*ay - 1.0f);
    R[5] = -s*ax + ic*ay*az;
    R[6] = -s*ay + ic*ax*az;
    R[7] =  s*ax + ic*ay*az;
    R[8] = 1.0f + ic*(az*az - 1.0f);
}

__global__ void init_kernel(const float* __restrict__ twist0, float* __restrict__ RT,
                            float* __restrict__ accum) {
    int tid = threadIdx.x;
    if (tid < B_*27) accum[tid] = 0.0f;
    if (tid < B_) {
        const float* w = twist0 + tid*6;
        float R[9];
        twist2mat_dev(w[0], w[1], w[2], R);
        float* rt = RT + tid*12;
        #pragma unroll
        for (int i = 0; i < 9; i++) rt[i] = R[i];
        rt[9] = w[3]; rt[10] = w[4]; rt[11] = w[5];
    }
}

// Iteration-invariant precompute: gx,gy (normalized sobel of x0), x0 center, sigma0^2
// packed as float4; x1/sigma1 interleaved as float2 for paired gathers.
__launch_bounds__(256)
__global__ void precompute_kernel(const float* __restrict__ x0, const float* __restrict__ x1,
                                  const float* __restrict__ sigma0, const float* __restrict__ sigma1,
                                  float4* __restrict__ P0, float2* __restrict__ X1S1)
{
    const int pix = blockIdx.x*256 + threadIdx.x;
    const int c = blockIdx.y;
    const int b = blockIdx.z;
    const int h = pix / W_, w = pix - h*W_;
    const size_t idx = ((size_t)(b*C_+c))*N_ + pix;
    const float* xc = x0 + ((size_t)(b*C_+c))*N_;
    const int hm = max(h-1,0), hp = min(h+1,H_-1);
    const int wm = max(w-1,0), wp = min(w+1,W_-1);
    const float tl = xc[hm*W_+wm], tc_ = xc[hm*W_+w], tr = xc[hm*W_+wp];
    const float ml = xc[h*W_+wm],                     mr = xc[h*W_+wp];
    const float bl = xc[hp*W_+wm], bc_ = xc[hp*W_+w], br = xc[hp*W_+wp];
    const float dx = tr - tl + 2.0f*(mr - ml) + (br - bl);
    const float dy = bl - tl + 2.0f*(bc_ - tc_) + (br - tr);
    const float mag = sqrtf(dx*dx + dy*dy + 1e-8f);
    const float gx = dx/mag, gy = dy/mag;
    const float s0 = sigma0[idx];
    P0[idx] = make_float4(gx, gy, xc[pix], s0*s0);
    X1S1[idx] = make_float2(x1[idx], sigma1[idx]);
}

__launch_bounds__(256)
__global__ void iter_kernel(const float4* __restrict__ P0, const float2* __restrict__ X1S1,
                            const float* __restrict__ invD0, const float* __restrict__ invD1,
                            const float* __restrict__ Kmat, const float* __restrict__ RT,
                            float* __restrict__ accum)
{
    const int b = blockIdx.y;
    const int pix = blockIdx.x * 256 + threadIdx.x;
    const int h = pix / W_;
    const int w = pix - h*W_;

    const float fx = Kmat[b*4+0], fy = Kmat[b*4+1], cx = Kmat[b*4+2], cy = Kmat[b*4+3];
    const float* rt = RT + b*12;
    const float R00=rt[0],R01=rt[1],R02=rt[2],R10=rt[3],R11=rt[4],R12=rt[5],
                R20=rt[6],R21=rt[7],R22=rt[8];
    const float t0=rt[9], t1=rt[10], t2=rt[11];

    float acc[27];
    #pragma unroll
    for (int j = 0; j < 27; j++) acc[j] = 0.0f;

    const float px = ((float)w - cx) / fx;
    const float py = ((float)h - cy) / fy;
    const float d  = invD0[b*N_ + pix];

    const float x_ = R00*px + R01*py + R02 + t0*d;
    const float y_ = R10*px + R11*py + R12 + t1*d;
    const float s_ = R20*px + R21*py + R22 + t2*d;
    const float u = x_/s_*fx + cx;
    const float v = y_/s_*fy + cy;
    const float inv_z = d / s_;

    const float uc = fminf(fmaxf(u, 0.0f), (float)(W_-1));
    const float vc = fminf(fmaxf(v, 0.0f), (float)(H_-1));
    const float x0f = floorf(uc), y0f = floorf(vc);
    const float wx = uc - x0f, wy = vc - y0f;
    const int x0i = (int)x0f, y0i = (int)y0f;
    const int x1i = min(x0i+1, W_-1), y1i = min(y0i+1, H_-1);
    const float w00 = (1.0f-wx)*(1.0f-wy), w01 = wx*(1.0f-wy);
    const float w10 = (1.0f-wx)*wy,        w11 = wx*wy;
    const int i00 = y0i*W_+x0i, i01 = y0i*W_+x1i, i10 = y1i*W_+x0i, i11 = y1i*W_+x1i;

    const float* dz = invD1 + b*N_;
    const float zw = dz[i00]*w00 + dz[i01]*w01 + dz[i10]*w10 + dz[i11]*w11;
    const bool inlier = inv_z > zw - 0.1f;
    const bool inview = (u > 0.0f) && (u < (float)W_) && (v > 0.0f) && (v < (float)H_);
    const bool valid  = inlier && inview;

    if (valid) {
        const float xy = px*py;
        const float Av[6] = { -xy*fx, (1.0f+px*px)*fx, -py*fx, d*fx, 0.0f, -d*px*fx };
        const float Bv[6] = { -(1.0f+py*py)*fy, xy*fy, px*fy, 0.0f, d*fy, -d*py*fy };

        float Swxx=0.f, Swxy=0.f, Swyy=0.f, Srx=0.f, Sry=0.f;
        const float4* p0b = P0   + (size_t)b*C_*N_;
        const float2* xsb = X1S1 + (size_t)b*C_*N_;
        #pragma unroll 4
        for (int c = 0; c < C_; c++) {
            const float4 p = p0b[c*N_ + pix];               // gx, gy, x0c, s0^2 (coalesced)
            const float2* xc = xsb + (size_t)c*N_;
            const float2 q00 = xc[i00], q01 = xc[i01], q10 = xc[i10], q11 = xc[i11];
            const float fr = q00.x*w00 + q01.x*w01 + q10.x*w10 + q11.x*w11;
            const float sr = q00.y*w00 + q01.y*w01 + q10.y*w10 + q11.y*w11;
            const float inv_s2 = 1.0f / (sr*sr + p.w);
            const float res = fr - p.z;
            Swxx += p.x*p.x*inv_s2;
            Swxy += p.x*p.y*inv_s2;
            Swyy += p.y*p.y*inv_s2;
            Srx  += p.x*res*inv_s2;
            Sry  += p.y*res*inv_s2;
        }
        int idx = 0;
        #pragma unroll
        for (int k = 0; k < 6; k++) {
            #pragma unroll
            for (int l = k; l < 6; l++) {
                acc[idx++] = Swxx*Av[k]*Av[l] + Swxy*(Av[k]*Bv[l] + Bv[k]*Av[l]) + Swyy*Bv[k]*Bv[l];
            }
        }
        #pragma unroll
        for (int k = 0; k < 6; k++) acc[21+k] = Srx*Av[k] + Sry*Bv[k];
    }

    const int lane = threadIdx.x & 63;
    const int wave = threadIdx.x >> 6;
    __shared__ float red[4][27];
    #pragma unroll
    for (int j = 0; j < 27; j++) {
        float vv = acc[j];
        vv += __shfl_down(vv, 32);
        vv += __shfl_down(vv, 16);
        vv += __shfl_down(vv, 8);
        vv += __shfl_down(vv, 4);
        vv += __shfl_down(vv, 2);
        vv += __shfl_down(vv, 1);
        if (lane == 0) red[wave][j] = vv;
    }
    __syncthreads();
    if (threadIdx.x < 27) {
        float s = red[0][threadIdx.x] + red[1][threadIdx.x] + red[2][threadIdx.x] + red[3][threadIdx.x];
        atomicAdd(&accum[b*27 + threadIdx.x], s);
    }
}

// Fallback (round-1 kernel) used if ws_size can't hold the precomputed tensors.
__launch_bounds__(256)
__global__ void reduce_kernel_fb(const float* __restrict__ x0, const float* __restrict__ x1,
                                 const float* __restrict__ invD0, const float* __restrict__ invD1,
                                 const float* __restrict__ sigma0, const float* __restrict__ sigma1,
                                 const float* __restrict__ Kmat, const float* __restrict__ RT,
                                 float* __restrict__ accum)
{
    const int b = blockIdx.y;
    const int pix = blockIdx.x * 256 + threadIdx.x;
    const int h = pix / W_;
    const int w = pix - h*W_;

    const float fx = Kmat[b*4+0], fy = Kmat[b*4+1], cx = Kmat[b*4+2], cy = Kmat[b*4+3];
    const float* rt = RT + b*12;
    const float R00=rt[0],R01=rt[1],R02=rt[2],R10=rt[3],R11=rt[4],R12=rt[5],
                R20=rt[6],R21=rt[7],R22=rt[8];
    const float t0=rt[9], t1=rt[10], t2=rt[11];

    float acc[27];
    #pragma unroll
    for (int j = 0; j < 27; j++) acc[j] = 0.0f;

    const float px = ((float)w - cx) / fx;
    const float py = ((float)h - cy) / fy;
    const float d  = invD0[b*N_ + pix];

    const float x_ = R00*px + R01*py + R02 + t0*d;
    const float y_ = R10*px + R11*py + R12 + t1*d;
    const float s_ = R20*px + R21*py + R22 + t2*d;
    const float u = x_/s_*fx + cx;
    const float v = y_/s_*fy + cy;
    const float inv_z = d / s_;

    const float uc = fminf(fmaxf(u, 0.0f), (float)(W_-1));
    const float vc = fminf(fmaxf(v, 0.0f), (float)(H_-1));
    const float x0f = floorf(uc), y0f = floorf(vc);
    const float wx = uc - x0f, wy = vc - y0f;
    const int x0i = (int)x0f, y0i = (int)y0f;
    const int x1i = min(x0i+1, W_-1), y1i = min(y0i+1, H_-1);
    const float w00 = (1.0f-wx)*(1.0f-wy), w01 = wx*(1.0f-wy);
    const float w10 = (1.0f-wx)*wy,        w11 = wx*wy;
    const int i00 = y0i*W_+x0i, i01 = y0i*W_+x1i, i10 = y1i*W_+x0i, i11 = y1i*W_+x1i;

    const float* dz = invD1 + b*N_;
    const float zw = dz[i00]*w00 + dz[i01]*w01 + dz[i10]*w10 + dz[i11]*w11;
    const bool inlier = inv_z > zw - 0.1f;
    const bool inview = (u > 0.0f) && (u < (float)W_) && (v > 0.0f) && (v < (float)H_);
    const bool valid  = inlier && inview;

    if (valid) {
        const float xy = px*py;
        const float Av[6] = { -xy*fx, (1.0f+px*px)*fx, -py*fx, d*fx, 0.0f, -d*px*fx };
        const float Bv[6] = { -(1.0f+py*py)*fy, xy*fy, px*fy, 0.0f, d*fy, -d*py*fy };

        const int hm = max(h-1,0), hp = min(h+1,H_-1);
        const int wm = max(w-1,0), wp = min(w+1,W_-1);

        float Swxx=0.f, Swxy=0.f, Swyy=0.f, Srx=0.f, Sry=0.f;
        const float* x0b = x0     + (size_t)b*C_*N_;
        const float* x1b = x1     + (size_t)b*C_*N_;
        const float* s0b = sigma0 + (size_t)b*C_*N_;
        const float* s1b = sigma1 + (size_t)b*C_*N_;
        for (int c = 0; c < C_; c++) {
            const float* xc = x0b + c*N_;
            const float tl = xc[hm*W_+wm], tc_ = xc[hm*W_+w], tr = xc[hm*W_+wp];
            const float ml = xc[h*W_+wm],                     mr = xc[h*W_+wp];
            const float bl = xc[hp*W_+wm], bc_ = xc[hp*W_+w], br = xc[hp*W_+wp];
            const float dx = tr - tl + 2.0f*(mr - ml) + (br - bl);
            const float dy = bl - tl + 2.0f*(bc_ - tc_) + (br - tr);
            const float mag = sqrtf(dx*dx + dy*dy + 1e-8f);
            const float gx = dx/mag, gy = dy/mag;

            const float* x1c = x1b + c*N_;
            const float fr = x1c[i00]*w00 + x1c[i01]*w01 + x1c[i10]*w10 + x1c[i11]*w11;
            const float* s1c = s1b + c*N_;
            const float sr = s1c[i00]*w00 + s1c[i01]*w01 + s1c[i10]*w10 + s1c[i11]*w11;
            const float s0v = s0b[c*N_ + pix];
            const float sig2 = sr*sr + s0v*s0v;
            const float inv_s2 = 1.0f / sig2;
            const float res = fr - xc[pix];
            Swxx += gx*gx*inv_s2;
            Swxy += gx*gy*inv_s2;
            Swyy += gy*gy*inv_s2;
            Srx  += gx*res*inv_s2;
            Sry  += gy*res*inv_s2;
        }
        int idx = 0;
        #pragma unroll
        for (int k = 0; k < 6; k++) {
            #pragma unroll
            for (int l = k; l < 6; l++) {
                acc[idx++] = Swxx*Av[k]*Av[l] + Swxy*(Av[k]*Bv[l] + Bv[k]*Av[l]) + Swyy*Bv[k]*Bv[l];
            }
        }
        #pragma unroll
        for (int k = 0; k < 6; k++) acc[21+k] = Srx*Av[k] + Sry*Bv[k];
    }

    const int lane = threadIdx.x & 63;
    const int wave = threadIdx.x >> 6;
    __shared__ float red[4][27];
    #pragma unroll
    for (int j = 0; j < 27; j++) {
        float vv = acc[j];
        vv += __shfl_down(vv, 32);
        vv += __shfl_down(vv, 16);
        vv += __shfl_down(vv, 8);
        vv += __shfl_down(vv, 4);
        vv += __shfl_down(vv, 2);
        vv += __shfl_down(vv, 1);
        if (lane == 0) red[wave][j] = vv;
    }
    __syncthreads();
    if (threadIdx.x < 27) {
        float s = red[0][threadIdx.x] + red[1][threadIdx.x] + red[2][threadIdx.x] + red[3][threadIdx.x];
        atomicAdd(&accum[b*27 + threadIdx.x], s);
    }
}

__global__ void solve_kernel(float* __restrict__ RT, float* __restrict__ accum,
                             float* __restrict__ out)
{
    const int b = threadIdx.x;
    if (b >= B_) return;
    float* ac = accum + b*27;

    float Hm[6][6];
    {
        int idx = 0;
        for (int k = 0; k < 6; k++)
            for (int l = k; l < 6; l++) { Hm[k][l] = ac[idx]; Hm[l][k] = ac[idx]; idx++; }
    }
    const float trace = Hm[0][0]+Hm[1][1]+Hm[2][2]+Hm[3][3]+Hm[4][4]+Hm[5][5];
    const float lam = trace * 1e-6f;

    float M[6][7];
    for (int i = 0; i < 6; i++) {
        for (int j = 0; j < 6; j++) M[i][j] = Hm[i][j];
        M[i][i] += lam;
        M[i][6] = ac[21+i];
    }
    for (int j = 0; j < 27; j++) ac[j] = 0.0f;

    for (int k = 0; k < 6; k++) {
        int p = k; float best = fabsf(M[k][k]);
        for (int i = k+1; i < 6; i++) {
            float a = fabsf(M[i][k]);
            if (a > best) { best = a; p = i; }
        }
        if (p != k) {
            for (int j = k; j < 7; j++) { float tmp = M[k][j]; M[k][j] = M[p][j]; M[p][j] = tmp; }
        }
        const float inv = 1.0f / M[k][k];
        for (int i = k+1; i < 6; i++) {
            const float f = M[i][k] * inv;
            for (int j = k; j < 7; j++) M[i][j] -= f * M[k][j];
        }
    }
    float xi[6];
    for (int i = 5; i >= 0; i--) {
        float s = M[i][6];
        for (int j = i+1; j < 6; j++) s -= M[i][j]*xi[j];
        xi[i] = s / M[i][i];
    }

    float dR[9];
    twist2mat_dev(-xi[0], -xi[1], -xi[2], dR);
    const float dt0 = -(dR[0]*xi[3] + dR[1]*xi[4] + dR[2]*xi[5]);
    const float dt1 = -(dR[3]*xi[3] + dR[4]*xi[4] + dR[5]*xi[5]);
    const float dt2 = -(dR[6]*xi[3] + dR[7]*xi[4] + dR[8]*xi[5]);

    float* rt = RT + b*12;
    float R[9];
    #pragma unroll
    for (int i = 0; i < 9; i++) R[i] = rt[i];
    const float t0 = rt[9], t1 = rt[10], t2 = rt[11];

    const float nt0 = R[0]*dt0 + R[1]*dt1 + R[2]*dt2 + t0;
    const float nt1 = R[3]*dt0 + R[4]*dt1 + R[5]*dt2 + t1;
    const float nt2 = R[6]*dt0 + R[7]*dt1 + R[8]*dt2 + t2;

    float nR[9];
    #pragma unroll
    for (int i = 0; i < 3; i++)
        #pragma unroll
        for (int j = 0; j < 3; j++)
            nR[i*3+j] = R[i*3+0]*dR[0*3+j] + R[i*3+1]*dR[1*3+j] + R[i*3+2]*dR[2*3+j];

    #pragma unroll
    for (int i = 0; i < 9; i++) rt[i] = nR[i];
    rt[9] = nt0; rt[10] = nt1; rt[11] = nt2;

    float* ob = out + b*12;
    #pragma unroll
    for (int i = 0; i < 9; i++) ob[i] = nR[i];
    ob[9] = nt0; ob[10] = nt1; ob[11] = nt2;
}

extern "C" void kernel_launch(void* const* d_in, const int* in_sizes, int n_in,
                              void* d_out, int out_size, void* d_ws, size_t ws_size,
                              hipStream_t stream) {
    const float* twist0 = (const float*)d_in[0];
    const float* x0     = (const float*)d_in[1];
    const float* x1     = (const float*)d_in[2];
    const float* invD0  = (const float*)d_in[3];
    const float* invD1  = (const float*)d_in[4];
    const float* sigma0 = (const float*)d_in[5];
    const float* sigma1 = (const float*)d_in[6];
    const float* Kmat   = (const float*)d_in[7];
    float* out = (float*)d_out;

    const size_t p0_bytes = (size_t)B_*C_*N_*sizeof(float4);   // 157 MB
    const size_t xs_bytes = (size_t)B_*C_*N_*sizeof(float2);   // 79 MB
    const size_t small_bytes = (size_t)(B_*12 + B_*27)*sizeof(float);

    if (ws_size >= p0_bytes + xs_bytes + small_bytes + 64) {
        float4* P0   = (float4*)d_ws;
        float2* X1S1 = (float2*)((char*)d_ws + p0_bytes);
        float*  RT   = (float*)((char*)d_ws + p0_bytes + xs_bytes);
        float*  accum = RT + B_*12;

        hipLaunchKernelGGL(init_kernel, dim3(1), dim3(256), 0, stream, twist0, RT, accum);
        hipLaunchKernelGGL(precompute_kernel, dim3(N_/256, C_, B_), dim3(256), 0, stream,
                           x0, x1, sigma0, sigma1, P0, X1S1);

        dim3 grid(N_/256, B_);
        for (int it = 0; it < 3; ++it) {
            hipLaunchKernelGGL(iter_kernel, grid, dim3(256), 0, stream,
                               P0, X1S1, invD0, invD1, Kmat, RT, accum);
            hipLaunchKernelGGL(solve_kernel, dim3(1), dim3(64), 0, stream, RT, accum, out);
        }
    } else {
        float* RT    = (float*)d_ws;
        float* accum = RT + B_*12;
        hipLaunchKernelGGL(init_kernel, dim3(1), dim3(256), 0, stream, twist0, RT, accum);
        dim3 grid(N_/256, B_);
        for (int it = 0; it < 3; ++it) {
            hipLaunchKernelGGL(reduce_kernel_fb, grid, dim3(256), 0, stream,
                               x0, x1, invD0, invD1, sigma0, sigma1, Kmat, RT, accum);
            hipLaunchKernelGGL(solve_kernel, dim3(1), dim3(64), 0, stream, RT, accum, out);
        }
    }
}

// Round 3
// 367.782 us; speedup vs baseline: 1.3528x; 1.1747x over previous
//
#include <hip/hip_runtime.h>
#include <hip/hip_fp16.h>

#define B_ 8
#define C_ 16
#define H_ 240
#define W_ 320
#define N_ (H_*W_)

__device__ __forceinline__ void twist2mat_dev(float w0, float w1, float w2, float R[9]) {
    float th = sqrtf(w0*w0 + w1*w1 + w2*w2) + 1e-12f;
    float ax = w0/th, ay = w1/th, az = w2/th;
    float s = sinf(th), c = cosf(th), ic = 1.0f - c;
    R[0] = 1.0f + ic*(ax*ax - 1.0f);
    R[1] = -s*az + ic*ax*ay;
    R[2] =  s*ay + ic*ax*az;
    R[3] =  s*az + ic*ax*ay;
    R[4] = 1.0f + ic*(ay*ay - 1.0f);
    R[5] = -s*ax + ic*ay*az;
    R[6] = -s*ay + ic*ax*az;
    R[7] =  s*ax + ic*ay*az;
    R[8] = 1.0f + ic*(az*az - 1.0f);
}

__global__ void init_kernel(const float* __restrict__ twist0, float* __restrict__ RT,
                            float* __restrict__ accum) {
    int tid = threadIdx.x;
    if (tid < B_*27) accum[tid] = 0.0f;
    if (tid < B_) {
        const float* w = twist0 + tid*6;
        float R[9];
        twist2mat_dev(w[0], w[1], w[2], R);
        float* rt = RT + tid*12;
        #pragma unroll
        for (int i = 0; i < 9; i++) rt[i] = R[i];
        rt[9] = w[3]; rt[10] = w[4]; rt[11] = w[5];
    }
}

__device__ __forceinline__ unsigned pack_h2(float a, float b) {
    __half2 h = __floats2half2_rn(a, b);
    return *reinterpret_cast<unsigned*>(&h);
}
__device__ __forceinline__ float2 unpack_h2(unsigned u) {
    __half2 h = *reinterpret_cast<__half2*>(&u);
    return __half22float2(h);
}

// Iteration-invariant precompute, fp16-packed:
//  P0h  (uint2 = half4): gx, gy, x0_center, sigma0^2   (8 B per c,pix)
//  X1S1h (uint = half2): x1, sigma1                     (4 B per c,pix)
__launch_bounds__(256)
__global__ void precompute_kernel(const float* __restrict__ x0, const float* __restrict__ x1,
                                  const float* __restrict__ sigma0, const float* __restrict__ sigma1,
                                  uint2* __restrict__ P0h, unsigned* __restrict__ X1S1h)
{
    const int pix = blockIdx.x*256 + threadIdx.x;
    const int c = blockIdx.y;
    const int b = blockIdx.z;
    const int h = pix / W_, w = pix - h*W_;
    const size_t idx = ((size_t)(b*C_+c))*N_ + pix;
    const float* xc = x0 + ((size_t)(b*C_+c))*N_;
    const int hm = max(h-1,0), hp = min(h+1,H_-1);
    const int wm = max(w-1,0), wp = min(w+1,W_-1);
    const float tl = xc[hm*W_+wm], tc_ = xc[hm*W_+w], tr = xc[hm*W_+wp];
    const float ml = xc[h*W_+wm],                     mr = xc[h*W_+wp];
    const float bl = xc[hp*W_+wm], bc_ = xc[hp*W_+w], br = xc[hp*W_+wp];
    const float dx = tr - tl + 2.0f*(mr - ml) + (br - bl);
    const float dy = bl - tl + 2.0f*(bc_ - tc_) + (br - tr);
    const float mag = sqrtf(dx*dx + dy*dy + 1e-8f);
    const float gx = dx/mag, gy = dy/mag;
    const float s0 = sigma0[idx];
    uint2 p;
    p.x = pack_h2(gx, gy);
    p.y = pack_h2(xc[pix], s0*s0);
    P0h[idx] = p;
    X1S1h[idx] = pack_h2(x1[idx], sigma1[idx]);
}

__launch_bounds__(256)
__global__ void iter_kernel(const uint2* __restrict__ P0h, const unsigned* __restrict__ X1S1h,
                            const float* __restrict__ invD0, const float* __restrict__ invD1,
                            const float* __restrict__ Kmat, const float* __restrict__ RT,
                            float* __restrict__ accum)
{
    const int b = blockIdx.y;
    const int pix = blockIdx.x * 256 + threadIdx.x;
    const int h = pix / W_;
    const int w = pix - h*W_;

    const float fx = Kmat[b*4+0], fy = Kmat[b*4+1], cx = Kmat[b*4+2], cy = Kmat[b*4+3];
    const float* rt = RT + b*12;
    const float R00=rt[0],R01=rt[1],R02=rt[2],R10=rt[3],R11=rt[4],R12=rt[5],
                R20=rt[6],R21=rt[7],R22=rt[8];
    const float t0=rt[9], t1=rt[10], t2=rt[11];

    float acc[27];
    #pragma unroll
    for (int j = 0; j < 27; j++) acc[j] = 0.0f;

    const float px = ((float)w - cx) / fx;
    const float py = ((float)h - cy) / fy;
    const float d  = invD0[b*N_ + pix];

    const float x_ = R00*px + R01*py + R02 + t0*d;
    const float y_ = R10*px + R11*py + R12 + t1*d;
    const float s_ = R20*px + R21*py + R22 + t2*d;
    const float u = x_/s_*fx + cx;
    const float v = y_/s_*fy + cy;
    const float inv_z = d / s_;

    const float uc = fminf(fmaxf(u, 0.0f), (float)(W_-1));
    const float vc = fminf(fmaxf(v, 0.0f), (float)(H_-1));
    const float x0f = floorf(uc), y0f = floorf(vc);
    const float wx = uc - x0f, wy = vc - y0f;
    const int x0i = (int)x0f, y0i = (int)y0f;
    const int x1i = min(x0i+1, W_-1), y1i = min(y0i+1, H_-1);
    const float w00 = (1.0f-wx)*(1.0f-wy), w01 = wx*(1.0f-wy);
    const float w10 = (1.0f-wx)*wy,        w11 = wx*wy;
    const int i00 = y0i*W_+x0i, i01 = y0i*W_+x1i, i10 = y1i*W_+x0i, i11 = y1i*W_+x1i;

    const float* dz = invD1 + b*N_;
    const float zw = dz[i00]*w00 + dz[i01]*w01 + dz[i10]*w10 + dz[i11]*w11;
    const bool inlier = inv_z > zw - 0.1f;
    const bool inview = (u > 0.0f) && (u < (float)W_) && (v > 0.0f) && (v < (float)H_);
    const bool valid  = inlier && inview;

    if (valid) {
        const float xy = px*py;
        const float Av[6] = { -xy*fx, (1.0f+px*px)*fx, -py*fx, d*fx, 0.0f, -d*px*fx };
        const float Bv[6] = { -(1.0f+py*py)*fy, xy*fy, px*fy, 0.0f, d*fy, -d*py*fy };

        float Swxx=0.f, Swxy=0.f, Swyy=0.f, Srx=0.f, Sry=0.f;
        const uint2*    p0b = P0h   + (size_t)b*C_*N_;
        const unsigned* xsb = X1S1h + (size_t)b*C_*N_;
        #pragma unroll
        for (int c = 0; c < C_; c++) {
            const uint2 praw = p0b[c*N_ + pix];             // coalesced 8B
            const unsigned* xc = xsb + (size_t)c*N_;
            const unsigned u00 = xc[i00], u01 = xc[i01], u10 = xc[i10], u11 = xc[i11];
            const float2 g  = unpack_h2(praw.x);            // gx, gy
            const float2 xs = unpack_h2(praw.y);            // x0c, s0^2
            const float2 q00 = unpack_h2(u00), q01 = unpack_h2(u01),
                         q10 = unpack_h2(u10), q11 = unpack_h2(u11);
            const float fr = q00.x*w00 + q01.x*w01 + q10.x*w10 + q11.x*w11;
            const float sr = q00.y*w00 + q01.y*w01 + q10.y*w10 + q11.y*w11;
            const float inv_s2 = 1.0f / (sr*sr + xs.y);
            const float res = fr - xs.x;
            const float gxw = g.x*inv_s2, gyw = g.y*inv_s2;
            Swxx += g.x*gxw;
            Swxy += g.x*gyw;
            Swyy += g.y*gyw;
            Srx  += res*gxw;
            Sry  += res*gyw;
        }
        int idx = 0;
        #pragma unroll
        for (int k = 0; k < 6; k++) {
            #pragma unroll
            for (int l = k; l < 6; l++) {
                acc[idx++] = Swxx*Av[k]*Av[l] + Swxy*(Av[k]*Bv[l] + Bv[k]*Av[l]) + Swyy*Bv[k]*Bv[l];
            }
        }
        #pragma unroll
        for (int k = 0; k < 6; k++) acc[21+k] = Srx*Av[k] + Sry*Bv[k];
    }

    const int lane = threadIdx.x & 63;
    const int wave = threadIdx.x >> 6;
    __shared__ float red[4][27];
    #pragma unroll
    for (int j = 0; j < 27; j++) {
        float vv = acc[j];
        vv += __shfl_down(vv, 32);
        vv += __shfl_down(vv, 16);
        vv += __shfl_down(vv, 8);
        vv += __shfl_down(vv, 4);
        vv += __shfl_down(vv, 2);
        vv += __shfl_down(vv, 1);
        if (lane == 0) red[wave][j] = vv;
    }
    __syncthreads();
    if (threadIdx.x < 27) {
        float s = red[0][threadIdx.x] + red[1][threadIdx.x] + red[2][threadIdx.x] + red[3][threadIdx.x];
        atomicAdd(&accum[b*27 + threadIdx.x], s);
    }
}

// Fallback (round-1 kernel) used if ws_size can't hold the precomputed tensors.
__launch_bounds__(256)
__global__ void reduce_kernel_fb(const float* __restrict__ x0, const float* __restrict__ x1,
                                 const float* __restrict__ invD0, const float* __restrict__ invD1,
                                 const float* __restrict__ sigma0, const float* __restrict__ sigma1,
                                 const float* __restrict__ Kmat, const float* __restrict__ RT,
                                 float* __restrict__ accum)
{
    const int b = blockIdx.y;
    const int pix = blockIdx.x * 256 + threadIdx.x;
    const int h = pix / W_;
    const int w = pix - h*W_;

    const float fx = Kmat[b*4+0], fy = Kmat[b*4+1], cx = Kmat[b*4+2], cy = Kmat[b*4+3];
    const float* rt = RT + b*12;
    const float R00=rt[0],R01=rt[1],R02=rt[2],R10=rt[3],R11=rt[4],R12=rt[5],
                R20=rt[6],R21=rt[7],R22=rt[8];
    const float t0=rt[9], t1=rt[10], t2=rt[11];

    float acc[27];
    #pragma unroll
    for (int j = 0; j < 27; j++) acc[j] = 0.0f;

    const float px = ((float)w - cx) / fx;
    const float py = ((float)h - cy) / fy;
    const float d  = invD0[b*N_ + pix];

    const float x_ = R00*px + R01*py + R02 + t0*d;
    const float y_ = R10*px + R11*py + R12 + t1*d;
    const float s_ = R20*px + R21*py + R22 + t2*d;
    const float u = x_/s_*fx + cx;
    const float v = y_/s_*fy + cy;
    const float inv_z = d / s_;

    const float uc = fminf(fmaxf(u, 0.0f), (float)(W_-1));
    const float vc = fminf(fmaxf(v, 0.0f), (float)(H_-1));
    const float x0f = floorf(uc), y0f = floorf(vc);
    const float wx = uc - x0f, wy = vc - y0f;
    const int x0i = (int)x0f, y0i = (int)y0f;
    const int x1i = min(x0i+1, W_-1), y1i = min(y0i+1, H_-1);
    const float w00 = (1.0f-wx)*(1.0f-wy), w01 = wx*(1.0f-wy);
    const float w10 = (1.0f-wx)*wy,        w11 = wx*wy;
    const int i00 = y0i*W_+x0i, i01 = y0i*W_+x1i, i10 = y1i*W_+x0i, i11 = y1i*W_+x1i;

    const float* dz = invD1 + b*N_;
    const float zw = dz[i00]*w00 + dz[i01]*w01 + dz[i10]*w10 + dz[i11]*w11;
    const bool inlier = inv_z > zw - 0.1f;
    const bool inview = (u > 0.0f) && (u < (float)W_) && (v > 0.0f) && (v < (float)H_);
    const bool valid  = inlier && inview;

    if (valid) {
        const float xy = px*py;
        const float Av[6] = { -xy*fx, (1.0f+px*px)*fx, -py*fx, d*fx, 0.0f, -d*px*fx };
        const float Bv[6] = { -(1.0f+py*py)*fy, xy*fy, px*fy, 0.0f, d*fy, -d*py*fy };

        const int hm = max(h-1,0), hp = min(h+1,H_-1);
        const int wm = max(w-1,0), wp = min(w+1,W_-1);

        float Swxx=0.f, Swxy=0.f, Swyy=0.f, Srx=0.f, Sry=0.f;
        const float* x0b = x0     + (size_t)b*C_*N_;
        const float* x1b = x1     + (size_t)b*C_*N_;
        const float* s0b = sigma0 + (size_t)b*C_*N_;
        const float* s1b = sigma1 + (size_t)b*C_*N_;
        for (int c = 0; c < C_; c++) {
            const float* xc = x0b + c*N_;
            const float tl = xc[hm*W_+wm], tc_ = xc[hm*W_+w], tr = xc[hm*W_+wp];
            const float ml = xc[h*W_+wm],                     mr = xc[h*W_+wp];
            const float bl = xc[hp*W_+wm], bc_ = xc[hp*W_+w], br = xc[hp*W_+wp];
            const float dx = tr - tl + 2.0f*(mr - ml) + (br - bl);
            const float dy = bl - tl + 2.0f*(bc_ - tc_) + (br - tr);
            const float mag = sqrtf(dx*dx + dy*dy + 1e-8f);
            const float gx = dx/mag, gy = dy/mag;

            const float* x1c = x1b + c*N_;
            const float fr = x1c[i00]*w00 + x1c[i01]*w01 + x1c[i10]*w10 + x1c[i11]*w11;
            const float* s1c = s1b + c*N_;
            const float sr = s1c[i00]*w00 + s1c[i01]*w01 + s1c[i10]*w10 + s1c[i11]*w11;
            const float s0v = s0b[c*N_ + pix];
            const float sig2 = sr*sr + s0v*s0v;
            const float inv_s2 = 1.0f / sig2;
            const float res = fr - xc[pix];
            Swxx += gx*gx*inv_s2;
            Swxy += gx*gy*inv_s2;
            Swyy += gy*gy*inv_s2;
            Srx  += gx*res*inv_s2;
            Sry  += gy*res*inv_s2;
        }
        int idx = 0;
        #pragma unroll
        for (int k = 0; k < 6; k++) {
            #pragma unroll
            for (int l = k; l < 6; l++) {
                acc[idx++] = Swxx*Av[k]*Av[l] + Swxy*(Av[k]*Bv[l] + Bv[k]*Av[l]) + Swyy*Bv[k]*Bv[l];
            }
        }
        #pragma unroll
        for (int k = 0; k < 6; k++) acc[21+k] = Srx*Av[k] + Sry*Bv[k];
    }

    const int lane = threadIdx.x & 63;
    const int wave = threadIdx.x >> 6;
    __shared__ float red[4][27];
    #pragma unroll
    for (int j = 0; j < 27; j++) {
        float vv = acc[j];
        vv += __shfl_down(vv, 32);
        vv += __shfl_down(vv, 16);
        vv += __shfl_down(vv, 8);
        vv += __shfl_down(vv, 4);
        vv += __shfl_down(vv, 2);
        vv += __shfl_down(vv, 1);
        if (lane == 0) red[wave][j] = vv;
    }
    __syncthreads();
    if (threadIdx.x < 27) {
        float s = red[0][threadIdx.x] + red[1][threadIdx.x] + red[2][threadIdx.x] + red[3][threadIdx.x];
        atomicAdd(&accum[b*27 + threadIdx.x], s);
    }
}

__global__ void solve_kernel(float* __restrict__ RT, float* __restrict__ accum,
                             float* __restrict__ out)
{
    const int b = threadIdx.x;
    if (b >= B_) return;
    float* ac = accum + b*27;

    float Hm[6][6];
    {
        int idx = 0;
        for (int k = 0; k < 6; k++)
            for (int l = k; l < 6; l++) { Hm[k][l] = ac[idx]; Hm[l][k] = ac[idx]; idx++; }
    }
    const float trace = Hm[0][0]+Hm[1][1]+Hm[2][2]+Hm[3][3]+Hm[4][4]+Hm[5][5];
    const float lam = trace * 1e-6f;

    float M[6][7];
    for (int i = 0; i < 6; i++) {
        for (int j = 0; j < 6; j++) M[i][j] = Hm[i][j];
        M[i][i] += lam;
        M[i][6] = ac[21+i];
    }
    for (int j = 0; j < 27; j++) ac[j] = 0.0f;

    for (int k = 0; k < 6; k++) {
        int p = k; float best = fabsf(M[k][k]);
        for (int i = k+1; i < 6; i++) {
            float a = fabsf(M[i][k]);
            if (a > best) { best = a; p = i; }
        }
        if (p != k) {
            for (int j = k; j < 7; j++) { float tmp = M[k][j]; M[k][j] = M[p][j]; M[p][j] = tmp; }
        }
        const float inv = 1.0f / M[k][k];
        for (int i = k+1; i < 6; i++) {
            const float f = M[i][k] * inv;
            for (int j = k; j < 7; j++) M[i][j] -= f * M[k][j];
        }
    }
    float xi[6];
    for (int i = 5; i >= 0; i--) {
        float s = M[i][6];
        for (int j = i+1; j < 6; j++) s -= M[i][j]*xi[j];
        xi[i] = s / M[i][i];
    }

    float dR[9];
    twist2mat_dev(-xi[0], -xi[1], -xi[2], dR);
    const float dt0 = -(dR[0]*xi[3] + dR[1]*xi[4] + dR[2]*xi[5]);
    const float dt1 = -(dR[3]*xi[3] + dR[4]*xi[4] + dR[5]*xi[5]);
    const float dt2 = -(dR[6]*xi[3] + dR[7]*xi[4] + dR[8]*xi[5]);

    float* rt = RT + b*12;
    float R[9];
    #pragma unroll
    for (int i = 0; i < 9; i++) R[i] = rt[i];
    const float t0 = rt[9], t1 = rt[10], t2 = rt[11];

    const float nt0 = R[0]*dt0 + R[1]*dt1 + R[2]*dt2 + t0;
    const float nt1 = R[3]*dt0 + R[4]*dt1 + R[5]*dt2 + t1;
    const float nt2 = R[6]*dt0 + R[7]*dt1 + R[8]*dt2 + t2;

    float nR[9];
    #pragma unroll
    for (int i = 0; i < 3; i++)
        #pragma unroll
        for (int j = 0; j < 3; j++)
            nR[i*3+j] = R[i*3+0]*dR[0*3+j] + R[i*3+1]*dR[1*3+j] + R[i*3+2]*dR[2*3+j];

    #pragma unroll
    for (int i = 0; i < 9; i++) rt[i] = nR[i];
    rt[9] = nt0; rt[10] = nt1; rt[11] = nt2;

    float* ob = out + b*12;
    #pragma unroll
    for (int i = 0; i < 9; i++) ob[i] = nR[i];
    ob[9] = nt0; ob[10] = nt1; ob[11] = nt2;
}

extern "C" void kernel_launch(void* const* d_in, const int* in_sizes, int n_in,
                              void* d_out, int out_size, void* d_ws, size_t ws_size,
                              hipStream_t stream) {
    const float* twist0 = (const float*)d_in[0];
    const float* x0     = (const float*)d_in[1];
    const float* x1     = (const float*)d_in[2];
    const float* invD0  = (const float*)d_in[3];
    const float* invD1  = (const float*)d_in[4];
    const float* sigma0 = (const float*)d_in[5];
    const float* sigma1 = (const float*)d_in[6];
    const float* Kmat   = (const float*)d_in[7];
    float* out = (float*)d_out;

    const size_t p0_bytes = (size_t)B_*C_*N_*sizeof(uint2);     // 78.6 MB
    const size_t xs_bytes = (size_t)B_*C_*N_*sizeof(unsigned);  // 39.3 MB
    const size_t small_bytes = (size_t)(B_*12 + B_*27)*sizeof(float);

    if (ws_size >= p0_bytes + xs_bytes + small_bytes + 64) {
        uint2*    P0h   = (uint2*)d_ws;
        unsigned* X1S1h = (unsigned*)((char*)d_ws + p0_bytes);
        float*    RT    = (float*)((char*)d_ws + p0_bytes + xs_bytes);
        float*    accum = RT + B_*12;

        hipLaunchKernelGGL(init_kernel, dim3(1), dim3(256), 0, stream, twist0, RT, accum);
        hipLaunchKernelGGL(precompute_kernel, dim3(N_/256, C_, B_), dim3(256), 0, stream,
                           x0, x1, sigma0, sigma1, P0h, X1S1h);

        dim3 grid(N_/256, B_);
        for (int it = 0; it < 3; ++it) {
            hipLaunchKernelGGL(iter_kernel, grid, dim3(256), 0, stream,
                               P0h, X1S1h, invD0, invD1, Kmat, RT, accum);
            hipLaunchKernelGGL(solve_kernel, dim3(1), dim3(64), 0, stream, RT, accum, out);
        }
    } else {
        float* RT    = (float*)d_ws;
        float* accum = RT + B_*12;
        hipLaunchKernelGGL(init_kernel, dim3(1), dim3(256), 0, stream, twist0, RT, accum);
        dim3 grid(N_/256, B_);
        for (int it = 0; it < 3; ++it) {
            hipLaunchKernelGGL(reduce_kernel_fb, grid, dim3(256), 0, stream,
                               x0, x1, invD0, invD1, sigma0, sigma1, Kmat, RT, accum);
            hipLaunchKernelGGL(solve_kernel, dim3(1), dim3(64), 0, stream, RT, accum, out);
        }
    }
}

// Round 4
// 362.133 us; speedup vs baseline: 1.3739x; 1.0156x over previous
//
#include <hip/hip_runtime.h>
#include <hip/hip_fp16.h>

#define B_ 8
#define C_ 16
#define H_ 240
#define W_ 320
#define N_ (H_*W_)

__device__ __forceinline__ void twist2mat_dev(float w0, float w1, float w2, float R[9]) {
    float th = sqrtf(w0*w0 + w1*w1 + w2*w2) + 1e-12f;
    float ax = w0/th, ay = w1/th, az = w2/th;
    float s = sinf(th), c = cosf(th), ic = 1.0f - c;
    R[0] = 1.0f + ic*(ax*ax - 1.0f);
    R[1] = -s*az + ic*ax*ay;
    R[2] =  s*ay + ic*ax*az;
    R[3] =  s*az + ic*ax*ay;
    R[4] = 1.0f + ic*(ay*ay - 1.0f);
    R[5] = -s*ax + ic*ay*az;
    R[6] = -s*ay + ic*ax*az;
    R[7] =  s*ax + ic*ay*az;
    R[8] = 1.0f + ic*(az*az - 1.0f);
}

__device__ __forceinline__ unsigned pack_h2(float a, float b) {
    __half2 h = __floats2half2_rn(a, b);
    return *reinterpret_cast<unsigned*>(&h);
}
__device__ __forceinline__ float2 unpack_h2(unsigned u) {
    __half2 h = *reinterpret_cast<__half2*>(&u);
    return __half22float2(h);
}

// One damped-GN solve step from accumulated [21 upper-tri JtWJ | 6 rhs]; updates R,t.
// Unpivoted Gaussian elimination, fully unrolled (SPD + damping -> stable).
__device__ __forceinline__ void solve_update(const float* __restrict__ ac, float R[9], float t[3]) {
    float M[6][7];
    {
        int idx = 0;
        #pragma unroll
        for (int k = 0; k < 6; k++)
            #pragma unroll
            for (int l = k; l < 6; l++) { M[k][l] = ac[idx]; M[l][k] = ac[idx]; idx++; }
    }
    const float trace = M[0][0]+M[1][1]+M[2][2]+M[3][3]+M[4][4]+M[5][5];
    const float lam = trace * 1e-6f;
    #pragma unroll
    for (int i = 0; i < 6; i++) { M[i][i] += lam; M[i][6] = ac[21+i]; }

    #pragma unroll
    for (int k = 0; k < 6; k++) {
        const float inv = 1.0f / M[k][k];
        #pragma unroll
        for (int i = k+1; i < 6; i++) {
            const float f = M[i][k] * inv;
            #pragma unroll
            for (int j = k; j < 7; j++) M[i][j] -= f * M[k][j];
        }
    }
    float xi[6];
    #pragma unroll
    for (int i = 5; i >= 0; i--) {
        float s = M[i][6];
        #pragma unroll
        for (int j = i+1; j < 6; j++) s -= M[i][j]*xi[j];
        xi[i] = s / M[i][i];
    }

    float dR[9];
    twist2mat_dev(-xi[0], -xi[1], -xi[2], dR);
    const float dt0 = -(dR[0]*xi[3] + dR[1]*xi[4] + dR[2]*xi[5]);
    const float dt1 = -(dR[3]*xi[3] + dR[4]*xi[4] + dR[5]*xi[5]);
    const float dt2 = -(dR[6]*xi[3] + dR[7]*xi[4] + dR[8]*xi[5]);

    const float nt0 = R[0]*dt0 + R[1]*dt1 + R[2]*dt2 + t[0];
    const float nt1 = R[3]*dt0 + R[4]*dt1 + R[5]*dt2 + t[1];
    const float nt2 = R[6]*dt0 + R[7]*dt1 + R[8]*dt2 + t[2];
    float nR[9];
    #pragma unroll
    for (int i = 0; i < 3; i++)
        #pragma unroll
        for (int j = 0; j < 3; j++)
            nR[i*3+j] = R[i*3+0]*dR[0*3+j] + R[i*3+1]*dR[1*3+j] + R[i*3+2]*dR[2*3+j];
    #pragma unroll
    for (int i = 0; i < 9; i++) R[i] = nR[i];
    t[0] = nt0; t[1] = nt1; t[2] = nt2;
}

__device__ __forceinline__ void build_RT(const float* __restrict__ twist0,
                                         const float* __restrict__ accum,
                                         int b, int iters, float R[9], float t[3]) {
    const float* w = twist0 + b*6;
    twist2mat_dev(w[0], w[1], w[2], R);
    t[0] = w[3]; t[1] = w[4]; t[2] = w[5];
    for (int j = 0; j < iters; j++)
        solve_update(accum + (size_t)(j*B_ + b)*27, R, t);
}

// Iteration-invariant precompute, 4 channels/thread:
//  P0h  : [b][cp=0..7][pix] uint4 = {h2(gx,gy), h2(x0,s0^2)} x 2 channels (16 B)
//  X1S1h: [b][cg=0..3][pix] uint4 = h2(x1,s1) x 4 channels (16 B, gather target)
// Block (0,0,0) also zeroes the 3 per-iteration accumulator sets.
__launch_bounds__(256)
__global__ void precompute_kernel(const float* __restrict__ x0, const float* __restrict__ x1,
                                  const float* __restrict__ sigma0, const float* __restrict__ sigma1,
                                  uint4* __restrict__ P0h, uint4* __restrict__ X1S1h,
                                  float* __restrict__ accum)
{
    if (blockIdx.x == 0 && blockIdx.y == 0 && blockIdx.z == 0) {
        for (int k = threadIdx.x; k < 3*B_*27; k += 256) accum[k] = 0.0f;
    }
    const int pix = blockIdx.x*256 + threadIdx.x;
    const int cg = blockIdx.y;
    const int b = blockIdx.z;
    const int h = pix / W_, w = pix - h*W_;
    const int hm = max(h-1,0), hp = min(h+1,H_-1);
    const int wm = max(w-1,0), wp = min(w+1,W_-1);

    unsigned p0[8];
    unsigned xsp[4];
    #pragma unroll
    for (int i = 0; i < 4; i++) {
        const int c = cg*4 + i;
        const size_t base = ((size_t)(b*C_+c))*N_;
        const float* xc = x0 + base;
        const float tl = xc[hm*W_+wm], tc_ = xc[hm*W_+w], tr = xc[hm*W_+wp];
        const float ml = xc[h*W_+wm],                     mr = xc[h*W_+wp];
        const float bl = xc[hp*W_+wm], bc_ = xc[hp*W_+w], br = xc[hp*W_+wp];
        const float dx = tr - tl + 2.0f*(mr - ml) + (br - bl);
        const float dy = bl - tl + 2.0f*(bc_ - tc_) + (br - tr);
        const float mag = sqrtf(dx*dx + dy*dy + 1e-8f);
        const float s0v = sigma0[base + pix];
        p0[i*2+0] = pack_h2(dx/mag, dy/mag);
        p0[i*2+1] = pack_h2(xc[pix], s0v*s0v);
        xsp[i] = pack_h2(x1[base + pix], sigma1[base + pix]);
    }
    uint4 a; a.x = p0[0]; a.y = p0[1]; a.z = p0[2]; a.w = p0[3];
    uint4 bb; bb.x = p0[4]; bb.y = p0[5]; bb.z = p0[6]; bb.w = p0[7];
    P0h[((size_t)(b*8 + cg*2  ))*N_ + pix] = a;
    P0h[((size_t)(b*8 + cg*2+1))*N_ + pix] = bb;
    uint4 q; q.x = xsp[0]; q.y = xsp[1]; q.z = xsp[2]; q.w = xsp[3];
    X1S1h[((size_t)(b*4 + cg))*N_ + pix] = q;
}

__launch_bounds__(256)
__global__ void iter_kernel(const uint4* __restrict__ P0h, const uint4* __restrict__ X1S1h,
                            const float* __restrict__ invD0, const float* __restrict__ invD1,
                            const float* __restrict__ Kmat, const float* __restrict__ twist0,
                            float* __restrict__ accum, int it)
{
    const int b = blockIdx.y;
    const int pix = blockIdx.x * 256 + threadIdx.x;
    const int h = pix / W_;
    const int w = pix - h*W_;

    // redundant per-thread solve chain (replaces separate init/solve dispatches)
    float Rm[9], tv[3];
    build_RT(twist0, accum, b, it, Rm, tv);

    const float fx = Kmat[b*4+0], fy = Kmat[b*4+1], cx = Kmat[b*4+2], cy = Kmat[b*4+3];

    float acc[27];
    #pragma unroll
    for (int j = 0; j < 27; j++) acc[j] = 0.0f;

    const float px = ((float)w - cx) / fx;
    const float py = ((float)h - cy) / fy;
    const float d  = invD0[b*N_ + pix];

    const float x_ = Rm[0]*px + Rm[1]*py + Rm[2] + tv[0]*d;
    const float y_ = Rm[3]*px + Rm[4]*py + Rm[5] + tv[1]*d;
    const float s_ = Rm[6]*px + Rm[7]*py + Rm[8] + tv[2]*d;
    const float u = x_/s_*fx + cx;
    const float v = y_/s_*fy + cy;
    const float inv_z = d / s_;

    const float uc = fminf(fmaxf(u, 0.0f), (float)(W_-1));
    const float vc = fminf(fmaxf(v, 0.0f), (float)(H_-1));
    const float x0f = floorf(uc), y0f = floorf(vc);
    const float wx = uc - x0f, wy = vc - y0f;
    const int x0i = (int)x0f, y0i = (int)y0f;
    const int x1i = min(x0i+1, W_-1), y1i = min(y0i+1, H_-1);
    const float w00 = (1.0f-wx)*(1.0f-wy), w01 = wx*(1.0f-wy);
    const float w10 = (1.0f-wx)*wy,        w11 = wx*wy;
    const int i00 = y0i*W_+x0i, i01 = y0i*W_+x1i, i10 = y1i*W_+x0i, i11 = y1i*W_+x1i;

    const float* dz = invD1 + b*N_;
    const float zw = dz[i00]*w00 + dz[i01]*w01 + dz[i10]*w10 + dz[i11]*w11;
    const bool inlier = inv_z > zw - 0.1f;
    const bool inview = (u > 0.0f) && (u < (float)W_) && (v > 0.0f) && (v < (float)H_);
    const bool valid  = inlier && inview;

    if (valid) {
        const float xy = px*py;
        const float Av[6] = { -xy*fx, (1.0f+px*px)*fx, -py*fx, d*fx, 0.0f, -d*px*fx };
        const float Bv[6] = { -(1.0f+py*py)*fy, xy*fy, px*fy, 0.0f, d*fy, -d*py*fy };

        float Swxx=0.f, Swxy=0.f, Swyy=0.f, Srx=0.f, Sry=0.f;
        const uint4* P0b   = P0h   + (size_t)b*8*N_;
        const uint4* X1S1b = X1S1h + (size_t)b*4*N_;

#define CH(gword, xword, t00, t01, t10, t11) { \
        const float2 g  = unpack_h2(gword); \
        const float2 xs = unpack_h2(xword); \
        const float2 a00 = unpack_h2(t00), a01 = unpack_h2(t01), \
                     a10 = unpack_h2(t10), a11 = unpack_h2(t11); \
        const float fr = a00.x*w00 + a01.x*w01 + a10.x*w10 + a11.x*w11; \
        const float sr = a00.y*w00 + a01.y*w01 + a10.y*w10 + a11.y*w11; \
        const float inv_s2 = 1.0f/(sr*sr + xs.y); \
        const float res = fr - xs.x; \
        const float gxw = g.x*inv_s2, gyw = g.y*inv_s2; \
        Swxx += g.x*gxw; Swxy += g.x*gyw; Swyy += g.y*gyw; \
        Srx  += res*gxw; Sry  += res*gyw; }

        #pragma unroll
        for (int cg = 0; cg < 4; cg++) {
            const uint4 pA = P0b[(size_t)(cg*2  )*N_ + pix];
            const uint4 pB = P0b[(size_t)(cg*2+1)*N_ + pix];
            const uint4* xsb = X1S1b + (size_t)cg*N_;
            const uint4 q00 = xsb[i00], q01 = xsb[i01], q10 = xsb[i10], q11 = xsb[i11];
            CH(pA.x, pA.y, q00.x, q01.x, q10.x, q11.x)
            CH(pA.z, pA.w, q00.y, q01.y, q10.y, q11.y)
            CH(pB.x, pB.y, q00.z, q01.z, q10.z, q11.z)
            CH(pB.z, pB.w, q00.w, q01.w, q10.w, q11.w)
        }
#undef CH

        int idx = 0;
        #pragma unroll
        for (int k = 0; k < 6; k++) {
            #pragma unroll
            for (int l = k; l < 6; l++) {
                acc[idx++] = Swxx*Av[k]*Av[l] + Swxy*(Av[k]*Bv[l] + Bv[k]*Av[l]) + Swyy*Bv[k]*Bv[l];
            }
        }
        #pragma unroll
        for (int k = 0; k < 6; k++) acc[21+k] = Srx*Av[k] + Sry*Bv[k];
    }

    const int lane = threadIdx.x & 63;
    const int wave = threadIdx.x >> 6;
    __shared__ float red[4][27];
    #pragma unroll
    for (int j = 0; j < 27; j++) {
        float vv = acc[j];
        vv += __shfl_down(vv, 32);
        vv += __shfl_down(vv, 16);
        vv += __shfl_down(vv, 8);
        vv += __shfl_down(vv, 4);
        vv += __shfl_down(vv, 2);
        vv += __shfl_down(vv, 1);
        if (lane == 0) red[wave][j] = vv;
    }
    __syncthreads();
    if (threadIdx.x < 27) {
        float s = red[0][threadIdx.x] + red[1][threadIdx.x] + red[2][threadIdx.x] + red[3][threadIdx.x];
        atomicAdd(&accum[(size_t)(it*B_ + b)*27 + threadIdx.x], s);
    }
}

__global__ void finalize_kernel(const float* __restrict__ twist0, const float* __restrict__ accum,
                                float* __restrict__ out)
{
    const int b = threadIdx.x;
    if (b >= B_) return;
    float Rm[9], tv[3];
    build_RT(twist0, accum, b, 3, Rm, tv);
    float* ob = out + b*12;
    #pragma unroll
    for (int i = 0; i < 9; i++) ob[i] = Rm[i];
    ob[9] = tv[0]; ob[10] = tv[1]; ob[11] = tv[2];
}

extern "C" void kernel_launch(void* const* d_in, const int* in_sizes, int n_in,
                              void* d_out, int out_size, void* d_ws, size_t ws_size,
                              hipStream_t stream) {
    const float* twist0 = (const float*)d_in[0];
    const float* x0     = (const float*)d_in[1];
    const float* x1     = (const float*)d_in[2];
    const float* invD0  = (const float*)d_in[3];
    const float* invD1  = (const float*)d_in[4];
    const float* sigma0 = (const float*)d_in[5];
    const float* sigma1 = (const float*)d_in[6];
    const float* Kmat   = (const float*)d_in[7];
    float* out = (float*)d_out;

    const size_t p0_bytes = (size_t)B_*8*N_*sizeof(uint4);   // 78.6 MB
    const size_t xs_bytes = (size_t)B_*4*N_*sizeof(uint4);   // 39.3 MB

    uint4* P0h   = (uint4*)d_ws;
    uint4* X1S1h = (uint4*)((char*)d_ws + p0_bytes);
    float* accum = (float*)((char*)d_ws + p0_bytes + xs_bytes);  // 3*B_*27 floats

    hipLaunchKernelGGL(precompute_kernel, dim3(N_/256, 4, B_), dim3(256), 0, stream,
                       x0, x1, sigma0, sigma1, P0h, X1S1h, accum);

    dim3 grid(N_/256, B_);
    for (int it = 0; it < 3; ++it) {
        hipLaunchKernelGGL(iter_kernel, grid, dim3(256), 0, stream,
                           P0h, X1S1h, invD0, invD1, Kmat, twist0, accum, it);
    }
    hipLaunchKernelGGL(finalize_kernel, dim3(1), dim3(64), 0, stream, twist0, accum, out);
}